// Round 1
// baseline (738.104 us; speedup 1.0000x reference)
//
#include <hip/hip_runtime.h>
#include <math.h>

#define N 8192
#define T 8192
#define RB 32
#define CB 32
#define HID 100
#define DIO (RB*CB)

#define ROWS_PER_BLOCK 64
#define COLS_PER_BLOCK 1024  // 256 threads * 4 floats

// K0: segment boundaries from sorted ids. rc[k] = first index i with id[i] >= k.
__global__ void k_bounds(const int* __restrict__ row_ids, const int* __restrict__ col_ids,
                         int* __restrict__ rc, int* __restrict__ cc) {
    int tid = blockIdx.x * blockDim.x + threadIdx.x;
    int stride = gridDim.x * blockDim.x;
    for (int i = tid; i < N; i += stride) {
        int a = row_ids[i];
        int b = (i + 1 < N) ? row_ids[i + 1] : RB;
        for (int k = a + 1; k <= b; ++k) rc[k] = i + 1;
        if (i == 0) { for (int k = 0; k <= a; ++k) rc[k] = 0; }
    }
    for (int i = tid; i < T; i += stride) {
        int a = col_ids[i];
        int b = (i + 1 < T) ? col_ids[i + 1] : CB;
        for (int k = a + 1; k <= b; ++k) cc[k] = i + 1;
        if (i == 0) { for (int k = 0; k <= a; ++k) cc[k] = 0; }
    }
}

// K1: one pass over X, accumulate per-(rowseg,colseg) sums.
// Block = 256 threads, covers 64 rows x 1024 cols. float4 loads (16B/lane).
// Sorted ids => row segment is wave-uniform per row; flush accumulators on
// segment change (rare). LDS 32x32 tile per block, nonzero entries atomicAdd'd
// to global blk[1024].
__global__ __launch_bounds__(256) void k_blocksum(const float* __restrict__ X,
        const int* __restrict__ row_ids, const int* __restrict__ col_ids,
        float* __restrict__ blk) {
    __shared__ float lblk[DIO];
    for (int i = threadIdx.x; i < DIO; i += 256) lblk[i] = 0.f;
    __syncthreads();

    const int colTile  = blockIdx.x & 7;
    const int rowChunk = blockIdx.x >> 3;
    const int c0 = colTile * COLS_PER_BLOCK + threadIdx.x * 4;

    // col segment of each of this thread's 4 columns (loaded once, L1-resident)
    const int cs0 = col_ids[c0 + 0];
    const int cs1 = col_ids[c0 + 1];
    const int cs2 = col_ids[c0 + 2];
    const int cs3 = col_ids[c0 + 3];

    const float4* __restrict__ X4 = (const float4*)X;
    const int i0 = rowChunk * ROWS_PER_BLOCK;
    const size_t cidx = (size_t)(c0 >> 2);

    float a0 = 0.f, a1 = 0.f, a2 = 0.f, a3 = 0.f;
    int cur = row_ids[i0];

    for (int i = i0; i < i0 + ROWS_PER_BLOCK; ++i) {
        int r = row_ids[i];            // uniform scalar load (sorted, rare change)
        if (r != cur) {                // wave-uniform branch, fires ~0-2x per block
            atomicAdd(&lblk[cur * CB + cs0], a0);
            atomicAdd(&lblk[cur * CB + cs1], a1);
            atomicAdd(&lblk[cur * CB + cs2], a2);
            atomicAdd(&lblk[cur * CB + cs3], a3);
            a0 = a1 = a2 = a3 = 0.f;
            cur = r;
        }
        float4 x = X4[(size_t)i * (T / 4) + cidx];
        a0 += x.x; a1 += x.y; a2 += x.z; a3 += x.w;
    }
    atomicAdd(&lblk[cur * CB + cs0], a0);
    atomicAdd(&lblk[cur * CB + cs1], a1);
    atomicAdd(&lblk[cur * CB + cs2], a2);
    atomicAdd(&lblk[cur * CB + cs3], a3);

    __syncthreads();
    for (int i = threadIdx.x; i < DIO; i += 256) {
        float v = lblk[i];
        if (v != 0.f) atomicAdd(&blk[i], v);   // ~12 nonzero entries per block
    }
}

// K2: finalize means, run the tiny MLP, sigmoid, emit outputs.
__global__ __launch_bounds__(128) void k_mlp(const float* __restrict__ blk,
        const int* __restrict__ rc, const int* __restrict__ cc,
        const float* __restrict__ W1, const float* __restrict__ b1,
        const float* __restrict__ W2, const float* __restrict__ b2,
        const float* __restrict__ W3, const float* __restrict__ b3,
        float* __restrict__ out) {
    __shared__ float x[DIO];
    __shared__ float h1[HID];
    __shared__ float h2[HID];
    __shared__ float rcs[RB + 1];
    __shared__ float ccs[CB + 1];
    const int t = threadIdx.x;

    if (t < RB + 1) rcs[t] = (float)rc[t];
    if (t < CB + 1) ccs[t] = (float)cc[t];
    __syncthreads();

    for (int i = t; i < DIO; i += 128) {
        int r = i >> 5, c = i & 31;
        float cnt = fmaxf((rcs[r + 1] - rcs[r]) * (ccs[c + 1] - ccs[c]), 1.0f);
        x[i] = blk[i] / cnt;
    }
    __syncthreads();

    if (t < HID) {
        float s = b1[t];
        for (int k = 0; k < DIO; ++k) s += x[k] * W1[k * HID + t];
        h1[t] = fmaxf(s, 0.f);
    }
    __syncthreads();

    if (t < HID) {
        float s = b2[t];
        for (int k = 0; k < HID; ++k) s += h1[k] * W2[k * HID + t];
        h2[t] = fmaxf(s, 0.f);
    }
    __syncthreads();

    for (int o = t; o < DIO; o += 128) {
        float s = b3[o];
        for (int k = 0; k < HID; ++k) s += h2[k] * W3[k * DIO + o];
        out[o] = 1.f / (1.f + expf(-s));
    }
    if (t < RB + 1) out[DIO + t] = rcs[t];
    if (t < CB + 1) out[DIO + RB + 1 + t] = ccs[t];
}

extern "C" void kernel_launch(void* const* d_in, const int* in_sizes, int n_in,
                              void* d_out, int out_size, void* d_ws, size_t ws_size,
                              hipStream_t stream) {
    const float* X       = (const float*)d_in[0];
    const int*   row_ids = (const int*)  d_in[1];
    const int*   col_ids = (const int*)  d_in[2];
    const float* W1      = (const float*)d_in[3];
    const float* b1      = (const float*)d_in[4];
    const float* W2      = (const float*)d_in[5];
    const float* b2      = (const float*)d_in[6];
    const float* W3      = (const float*)d_in[7];
    const float* b3      = (const float*)d_in[8];
    float* out = (float*)d_out;

    float* blk = (float*)d_ws;
    int*   rc  = (int*)((char*)d_ws + DIO * sizeof(float));
    int*   cc  = rc + (RB + 1);

    // ws is poisoned to 0xAA before every launch — zero the accumulator.
    hipMemsetAsync(d_ws, 0, DIO * sizeof(float), stream);

    k_bounds<<<16, 256, 0, stream>>>(row_ids, col_ids, rc, cc);
    k_blocksum<<<(T / COLS_PER_BLOCK) * (N / ROWS_PER_BLOCK), 256, 0, stream>>>(
        X, row_ids, col_ids, blk);
    k_mlp<<<1, 128, 0, stream>>>(blk, rc, cc, W1, b1, W2, b2, W3, b3, out);
}

// Round 2
// 424.205 us; speedup vs baseline: 1.7400x; 1.7400x over previous
//
#include <hip/hip_runtime.h>
#include <math.h>

#define N 8192
#define T 8192
#define RB 32
#define CB 32
#define HID 100
#define DIO (RB*CB)

#define ROWS_PER_BLOCK 64
#define COLS_PER_BLOCK 1024   // 256 threads * 4 floats
#define NBLK ((T/COLS_PER_BLOCK)*(N/ROWS_PER_BLOCK))
#define K1BLOCKS 32           // layer-1 K-parallel blocks
#define KCHUNK (DIO/K1BLOCKS) // 32 inputs per block

// K0: segment boundaries from sorted ids. rc[k] = first index i with id[i] >= k.
__global__ void k_bounds(const int* __restrict__ row_ids, const int* __restrict__ col_ids,
                         int* __restrict__ rc, int* __restrict__ cc) {
    int tid = blockIdx.x * blockDim.x + threadIdx.x;
    int stride = gridDim.x * blockDim.x;
    for (int i = tid; i < N; i += stride) {
        int a = row_ids[i];
        int b = (i + 1 < N) ? row_ids[i + 1] : RB;
        for (int k = a + 1; k <= b; ++k) rc[k] = i + 1;
        if (i == 0) { for (int k = 0; k <= a; ++k) rc[k] = 0; }
    }
    for (int i = tid; i < T; i += stride) {
        int a = col_ids[i];
        int b = (i + 1 < T) ? col_ids[i + 1] : CB;
        for (int k = a + 1; k <= b; ++k) cc[k] = i + 1;
        if (i == 0) { for (int k = 0; k <= a; ++k) cc[k] = 0; }
    }
}

// K1: one pass over X. Fast path: 64-row chunk entirely in one row segment
// (block-uniform, ~97% of blocks) -> fixed-trip branch-free loop, 8 float4
// loads in flight. Slow path: walk segments via rc[] (no per-row id loads).
__global__ __launch_bounds__(256) void k_blocksum(const float* __restrict__ X,
        const int* __restrict__ row_ids, const int* __restrict__ col_ids,
        const int* __restrict__ rc, float* __restrict__ blk) {
    __shared__ float lblk[DIO];
    __shared__ int src[RB + 1];
    for (int i = threadIdx.x; i < DIO; i += 256) lblk[i] = 0.f;
    if (threadIdx.x < RB + 1) src[threadIdx.x] = rc[threadIdx.x];
    __syncthreads();

    const int colTile  = blockIdx.x & 7;
    const int rowChunk = blockIdx.x >> 3;
    const int c0 = colTile * COLS_PER_BLOCK + threadIdx.x * 4;

    const int cs0 = col_ids[c0 + 0];
    const int cs1 = col_ids[c0 + 1];
    const int cs2 = col_ids[c0 + 2];
    const int cs3 = col_ids[c0 + 3];

    const float4* __restrict__ X4 = (const float4*)X;
    const int i0   = rowChunk * ROWS_PER_BLOCK;
    const int iend = i0 + ROWS_PER_BLOCK;
    const size_t cidx = (size_t)(c0 >> 2);

    const int sFirst = row_ids[i0];
    const int sLast  = row_ids[iend - 1];

    if (sFirst == sLast) {
        float a0 = 0.f, a1 = 0.f, a2 = 0.f, a3 = 0.f;
        #pragma unroll 8
        for (int i = i0; i < iend; ++i) {
            float4 x = X4[(size_t)i * (T / 4) + cidx];
            a0 += x.x; a1 += x.y; a2 += x.z; a3 += x.w;
        }
        atomicAdd(&lblk[sFirst * CB + cs0], a0);
        atomicAdd(&lblk[sFirst * CB + cs1], a1);
        atomicAdd(&lblk[sFirst * CB + cs2], a2);
        atomicAdd(&lblk[sFirst * CB + cs3], a3);
    } else {
        int i = i0;
        int s = sFirst;
        while (i < iend) {
            int hi = min(src[s + 1], iend);
            float a0 = 0.f, a1 = 0.f, a2 = 0.f, a3 = 0.f;
            for (; i < hi; ++i) {
                float4 x = X4[(size_t)i * (T / 4) + cidx];
                a0 += x.x; a1 += x.y; a2 += x.z; a3 += x.w;
            }
            atomicAdd(&lblk[s * CB + cs0], a0);
            atomicAdd(&lblk[s * CB + cs1], a1);
            atomicAdd(&lblk[s * CB + cs2], a2);
            atomicAdd(&lblk[s * CB + cs3], a3);
            ++s;
        }
    }

    __syncthreads();
    for (int i = threadIdx.x; i < DIO; i += 256) {
        float v = lblk[i];
        if (v != 0.f) atomicAdd(&blk[i], v);
    }
}

// K2a: layer-1 partials, K-parallel over 32 blocks. Block b handles inputs
// k in [32b, 32b+32); coalesced W1 row loads; deterministic partial write.
__global__ __launch_bounds__(128) void k_mlp1(const float* __restrict__ blk,
        const int* __restrict__ rc, const int* __restrict__ cc,
        const float* __restrict__ W1, float* __restrict__ part1) {
    __shared__ float xs[KCHUNK];
    const int b = blockIdx.x, t = threadIdx.x;
    const int k0 = b * KCHUNK;
    if (t < KCHUNK) {
        int k = k0 + t;
        int r = k >> 5, c = k & 31;
        float cnt = fmaxf((float)(rc[r + 1] - rc[r]) * (float)(cc[c + 1] - cc[c]), 1.0f);
        xs[t] = blk[k] / cnt;
    }
    __syncthreads();
    if (t < HID) {
        float s = 0.f;
        #pragma unroll 8
        for (int kk = 0; kk < KCHUNK; ++kk)
            s += xs[kk] * W1[(size_t)(k0 + kk) * HID + t];
        part1[b * HID + t] = s;
    }
}

// K2b: reduce layer-1 partials + relu, layer 2 + relu -> h2; emit cumsums.
__global__ __launch_bounds__(128) void k_mlp2(const float* __restrict__ part1,
        const float* __restrict__ b1, const float* __restrict__ W2,
        const float* __restrict__ b2, const int* __restrict__ rc,
        const int* __restrict__ cc, float* __restrict__ h2out,
        float* __restrict__ out) {
    __shared__ float h1[HID];
    const int t = threadIdx.x;
    if (t < HID) {
        float s = b1[t];
        #pragma unroll 8
        for (int b = 0; b < K1BLOCKS; ++b) s += part1[b * HID + t];
        h1[t] = fmaxf(s, 0.f);
    }
    __syncthreads();
    if (t < HID) {
        float s = b2[t];
        #pragma unroll 4
        for (int k = 0; k < HID; ++k) s += h1[k] * W2[k * HID + t];
        h2out[t] = fmaxf(s, 0.f);
    }
    if (t < RB + 1) out[DIO + t] = (float)rc[t];
    if (t < CB + 1) out[DIO + RB + 1 + t] = (float)cc[t];
}

// K2c: layer 3 + sigmoid, output-parallel over 8 blocks (W3 coalesced at fixed k).
__global__ __launch_bounds__(128) void k_mlp3(const float* __restrict__ h2,
        const float* __restrict__ W3, const float* __restrict__ b3,
        float* __restrict__ out) {
    __shared__ float h[HID];
    const int t = threadIdx.x;
    if (t < HID) h[t] = h2[t];
    __syncthreads();
    const int o = blockIdx.x * 128 + t;
    float s = b3[o];
    #pragma unroll 4
    for (int k = 0; k < HID; ++k) s += h[k] * W3[k * DIO + o];
    out[o] = 1.f / (1.f + expf(-s));
}

extern "C" void kernel_launch(void* const* d_in, const int* in_sizes, int n_in,
                              void* d_out, int out_size, void* d_ws, size_t ws_size,
                              hipStream_t stream) {
    const float* X       = (const float*)d_in[0];
    const int*   row_ids = (const int*)  d_in[1];
    const int*   col_ids = (const int*)  d_in[2];
    const float* W1      = (const float*)d_in[3];
    const float* b1      = (const float*)d_in[4];
    const float* W2      = (const float*)d_in[5];
    const float* b2      = (const float*)d_in[6];
    const float* W3      = (const float*)d_in[7];
    const float* b3      = (const float*)d_in[8];
    float* out = (float*)d_out;

    float* blk   = (float*)d_ws;              // 1024
    float* part1 = blk + DIO;                 // 32*100
    float* h2    = part1 + K1BLOCKS * HID;    // 100
    int*   rc    = (int*)(h2 + HID);          // 33
    int*   cc    = rc + (RB + 1);             // 33

    // ws is poisoned to 0xAA before every launch — zero the accumulator.
    hipMemsetAsync(blk, 0, DIO * sizeof(float), stream);

    k_bounds<<<16, 256, 0, stream>>>(row_ids, col_ids, rc, cc);
    k_blocksum<<<NBLK, 256, 0, stream>>>(X, row_ids, col_ids, rc, blk);
    k_mlp1<<<K1BLOCKS, 128, 0, stream>>>(blk, rc, cc, W1, part1);
    k_mlp2<<<1, 128, 0, stream>>>(part1, b1, W2, b2, rc, cc, h2, out);
    k_mlp3<<<DIO / 128, 128, 0, stream>>>(h2, W3, b3, out);
}